// Round 2
// baseline (1553.515 us; speedup 1.0000x reference)
//
#include <hip/hip_runtime.h>
#include <hip/hip_bf16.h>
#include <math.h>

#define N_NODES 50000
#define E_EDGES 800000
#define IN_DIM  512
#define HDIM    128
#define CDIM    40
#define LAYERS  8

// ---------------- CSR build ----------------

__global__ void hist_kernel(const int* __restrict__ dst, int* __restrict__ cnt) {
    int i = blockIdx.x * blockDim.x + threadIdx.x;
    if (i < E_EDGES) atomicAdd(&cnt[dst[i]], 1);
}

__global__ void scan_kernel(const int* __restrict__ cnt, int* __restrict__ row_start) {
    __shared__ int partial[1024];
    const int n = N_NODES;
    int t = threadIdx.x;
    int chunk = (n + 1023) >> 10;
    int lo = t * chunk;
    int hi = lo + chunk; if (hi > n) hi = n;
    int s = 0;
    for (int i = lo; i < hi; i++) s += cnt[i];
    partial[t] = s;
    __syncthreads();
    for (int d = 1; d < 1024; d <<= 1) {
        int v = (t >= d) ? partial[t - d] : 0;
        __syncthreads();
        partial[t] += v;
        __syncthreads();
    }
    int base = (t > 0) ? partial[t - 1] : 0;
    for (int i = lo; i < hi; i++) { row_start[i] = base; base += cnt[i]; }
    if (t == 1023) row_start[n] = partial[1023];
}

__global__ void scatter_kernel(const int* __restrict__ ei, const float* __restrict__ normA,
                               int* __restrict__ cursor,
                               int* __restrict__ perm_src, float* __restrict__ perm_w) {
    int i = blockIdx.x * blockDim.x + threadIdx.x;
    if (i >= E_EDGES) return;
    int d = ei[E_EDGES + i];
    int idx = atomicAdd(&cursor[d], 1);
    perm_src[idx] = ei[i];
    perm_w[idx]   = normA[i];
}

// ---------------- fc0: x = relu(F @ W0 + b0), write to h0 and xA ----------------

__global__ void fc0_kernel(const float* __restrict__ F, const float* __restrict__ W0,
                           const float* __restrict__ b0,
                           float* __restrict__ h0, float* __restrict__ xA) {
    __shared__ float fs[8][IN_DIM];   // 16 KB
    int h = threadIdx.x;              // 0..127
    int row0 = blockIdx.x * 8;
    for (int i = threadIdx.x; i < 8 * IN_DIM; i += 128) {
        int r = i >> 9, k = i & (IN_DIM - 1);
        fs[r][k] = F[(size_t)(row0 + r) * IN_DIM + k];
    }
    __syncthreads();
    float acc[8];
#pragma unroll
    for (int r = 0; r < 8; r++) acc[r] = 0.f;
    for (int k = 0; k < IN_DIM; k++) {
        float w = W0[k * HDIM + h];
#pragma unroll
        for (int r = 0; r < 8; r++) acc[r] += fs[r][k] * w;
    }
    float bias = b0[h];
#pragma unroll
    for (int r = 0; r < 8; r++) {
        float v = acc[r] + bias;
        v = v > 0.f ? v : 0.f;
        h0[(size_t)(row0 + r) * HDIM + h] = v;
        xA[(size_t)(row0 + r) * HDIM + h] = v;
    }
}

// ---------------- SpMM + residual mix: sup = 0.9*(A x) + 0.1*h0 ----------------

__global__ void spmm_kernel(const int* __restrict__ row_start,
                            const int* __restrict__ perm_src,
                            const float* __restrict__ perm_w,
                            const float* __restrict__ x,
                            const float* __restrict__ h0,
                            float* __restrict__ sup) {
    int row  = blockIdx.x * 4 + (threadIdx.x >> 6);
    int lane = threadIdx.x & 63;
    if (row >= N_NODES) return;
    int e0 = row_start[row], e1 = row_start[row + 1];
    float a0 = 0.f, a1 = 0.f;
    for (int e = e0; e < e1; e++) {
        int   s = perm_src[e];
        float w = perm_w[e];
        float2 v = *(const float2*)(x + (size_t)s * HDIM + lane * 2);
        a0 += w * v.x;
        a1 += w * v.y;
    }
    float2 h = *(const float2*)(h0 + (size_t)row * HDIM + lane * 2);
    float2 o;
    o.x = 0.9f * a0 + 0.1f * h.x;
    o.y = 0.9f * a1 + 0.1f * h.y;
    *(float2*)(sup + (size_t)row * HDIM + lane * 2) = o;
}

// ---------- layer GEMM: x = relu(beta*(S@W) + (1-beta)*S) ----------

__global__ void layer_gemm(const float* __restrict__ sup, const float* __restrict__ W,
                           float* __restrict__ xout, float beta) {
    __shared__ float ss[8][HDIM];     // 4 KB
    int h = threadIdx.x;
    int row0 = blockIdx.x * 8;
    for (int i = threadIdx.x; i < 8 * HDIM; i += 128) {
        int r = i >> 7, k = i & (HDIM - 1);
        ss[r][k] = sup[(size_t)(row0 + r) * HDIM + k];
    }
    __syncthreads();
    float acc[8];
#pragma unroll
    for (int r = 0; r < 8; r++) acc[r] = 0.f;
    for (int k = 0; k < HDIM; k++) {
        float w = W[k * HDIM + h];
#pragma unroll
        for (int r = 0; r < 8; r++) acc[r] += ss[r][k] * w;
    }
    float g = 1.0f - beta;
#pragma unroll
    for (int r = 0; r < 8; r++) {
        float v = beta * acc[r] + g * ss[r][h];
        xout[(size_t)(row0 + r) * HDIM + h] = v > 0.f ? v : 0.f;
    }
}

// ---------------- fc1: out = x @ W1 + b1 (fp32 out) ----------------

__global__ void fc1_kernel(const float* __restrict__ x, const float* __restrict__ W1,
                           const float* __restrict__ b1, float* __restrict__ out) {
    int idx = blockIdx.x * blockDim.x + threadIdx.x;
    if (idx >= N_NODES * CDIM) return;
    int r = idx / CDIM;
    int c = idx - r * CDIM;
    float acc = b1[c];
    for (int k = 0; k < HDIM; k++)
        acc += x[(size_t)r * HDIM + k] * W1[k * CDIM + c];
    out[idx] = acc;
}

// ---------------- launch ----------------

extern "C" void kernel_launch(void* const* d_in, const int* in_sizes, int n_in,
                              void* d_out, int out_size, void* d_ws, size_t ws_size,
                              hipStream_t stream) {
    const float* F     = (const float*)d_in[0];
    const int*   ei    = (const int*)d_in[1];
    const float* normA = (const float*)d_in[2];
    const float* W0    = (const float*)d_in[3];
    const float* b0    = (const float*)d_in[4];
    const float* convW = (const float*)d_in[5];
    const float* W1    = (const float*)d_in[6];
    const float* b1    = (const float*)d_in[7];
    float*       out   = (float*)d_out;

    // workspace layout (~84 MB)
    float* h0        = (float*)d_ws;
    float* xA        = h0 + (size_t)N_NODES * HDIM;
    float* xB        = xA + (size_t)N_NODES * HDIM;
    int*   row_start = (int*)(xB + (size_t)N_NODES * HDIM);
    int*   cursor    = row_start + (N_NODES + 2);
    int*   perm_src  = cursor + (N_NODES + 2);
    float* perm_w    = (float*)(perm_src + E_EDGES);

    // CSR build (amortized over 8 spmm layers)
    hipMemsetAsync(cursor, 0, N_NODES * sizeof(int), stream);
    hist_kernel<<<(E_EDGES + 255) / 256, 256, 0, stream>>>(ei + E_EDGES, cursor);
    scan_kernel<<<1, 1024, 0, stream>>>(cursor, row_start);
    hipMemcpyAsync(cursor, row_start, N_NODES * sizeof(int),
                   hipMemcpyDeviceToDevice, stream);
    scatter_kernel<<<(E_EDGES + 255) / 256, 256, 0, stream>>>(ei, normA, cursor,
                                                              perm_src, perm_w);

    fc0_kernel<<<N_NODES / 8, 128, 0, stream>>>(F, W0, b0, h0, xA);

    for (int i = 0; i < LAYERS; i++) {
        float beta = logf(0.5f / (float)(i + 1) + 1.0f);
        spmm_kernel<<<(N_NODES + 3) / 4, 256, 0, stream>>>(row_start, perm_src, perm_w,
                                                           xA, h0, xB);
        layer_gemm<<<N_NODES / 8, 128, 0, stream>>>(
            xB, convW + (size_t)i * HDIM * HDIM, xA, beta);
    }

    fc1_kernel<<<(N_NODES * CDIM + 255) / 256, 256, 0, stream>>>(xA, W1, b1, out);
}

// Round 3
// 1048.523 us; speedup vs baseline: 1.4816x; 1.4816x over previous
//
#include <hip/hip_runtime.h>
#include <hip/hip_bf16.h>
#include <math.h>

#define N_NODES 50000
#define M_PAD   50048           // 782 blocks * 64 rows
#define E_EDGES 800000
#define IN_DIM  512
#define HDIM    128
#define CDIM    40
#define LAYERS  8

typedef __attribute__((ext_vector_type(8))) short short8;
typedef __attribute__((ext_vector_type(4))) float floatx4;
typedef unsigned short ushort_t;

__device__ inline float bf2f(unsigned short u) {
    return __uint_as_float(((unsigned)u) << 16);
}
__device__ inline unsigned short f2bf(float v) {
    __hip_bfloat16 b = __float2bfloat16(v);
    return *reinterpret_cast<unsigned short*>(&b);
}
__device__ inline unsigned pack2(float lo, float hi) {
    return (unsigned)f2bf(lo) | ((unsigned)f2bf(hi) << 16);
}

// ---------------- CSR build ----------------

__global__ void hist_kernel(const int* __restrict__ dst, int* __restrict__ cnt) {
    int i = blockIdx.x * blockDim.x + threadIdx.x;
    if (i < E_EDGES) atomicAdd(&cnt[dst[i]], 1);
}

__global__ void scan_kernel(const int* __restrict__ cnt, int* __restrict__ row_start) {
    __shared__ int partial[1024];
    const int n = N_NODES;
    int t = threadIdx.x;
    int chunk = (n + 1023) >> 10;
    int lo = t * chunk;
    int hi = lo + chunk; if (hi > n) hi = n;
    int s = 0;
    for (int i = lo; i < hi; i++) s += cnt[i];
    partial[t] = s;
    __syncthreads();
    for (int d = 1; d < 1024; d <<= 1) {
        int v = (t >= d) ? partial[t - d] : 0;
        __syncthreads();
        partial[t] += v;
        __syncthreads();
    }
    int base = (t > 0) ? partial[t - 1] : 0;
    for (int i = lo; i < hi; i++) { row_start[i] = base; base += cnt[i]; }
    if (t == 1023) row_start[n] = partial[1023];
}

__global__ void scatter_kernel(const int* __restrict__ ei, const float* __restrict__ normA,
                               int* __restrict__ cursor,
                               int* __restrict__ perm_src, float* __restrict__ perm_w) {
    int i = blockIdx.x * blockDim.x + threadIdx.x;
    if (i >= E_EDGES) return;
    int d = ei[E_EDGES + i];
    int idx = atomicAdd(&cursor[d], 1);
    perm_src[idx] = ei[i];
    perm_w[idx]   = normA[i];
}

// ---------------- weight prep: transpose + bf16 convert ----------------
// Wt0[n][k] (128x512), WtL[l][n][k] (8 x 128x128), Wt1[n][k] (48x128, rows>=40 zero)

__global__ void prep_weights(const float* __restrict__ W0, const float* __restrict__ convW,
                             const float* __restrict__ W1,
                             ushort_t* __restrict__ Wt0, ushort_t* __restrict__ WtL,
                             ushort_t* __restrict__ Wt1) {
    int i = blockIdx.x * blockDim.x + threadIdx.x;
    if (i < 128 * 512) {
        int n = i >> 9, k = i & 511;
        Wt0[i] = f2bf(W0[k * HDIM + n]);
        return;
    }
    int j = i - 128 * 512;
    if (j < 8 * 128 * 128) {
        int l = j >> 14, rem = j & 16383, n = rem >> 7, k = rem & 127;
        WtL[j] = f2bf(convW[l * 16384 + k * HDIM + n]);
        return;
    }
    int m = j - 8 * 128 * 128;
    if (m < 48 * 128) {
        int n = m >> 7, k = m & 127;
        Wt1[m] = (n < CDIM) ? f2bf(W1[k * CDIM + n]) : (ushort_t)0;
    }
}

// ---------------- fc0: x = relu(F @ W0 + b0) -> h0b, xab (bf16) ----------------
// wave computes 16 rows x 128 cols; K=512 in 16 MFMA K-steps

__global__ void fc0_mfma(const float* __restrict__ F, const ushort_t* __restrict__ Wt0,
                         const float* __restrict__ b0,
                         ushort_t* __restrict__ h0b, ushort_t* __restrict__ xab) {
    int wave = threadIdx.x >> 6;
    int lane = threadIdx.x & 63;
    int quad = lane >> 4, l16 = lane & 15;
    int row0 = blockIdx.x * 64 + wave * 16;

    int arow = row0 + l16; if (arow > N_NODES - 1) arow = N_NODES - 1;
    const float* fp = F + (size_t)arow * IN_DIM + quad * 8;

    floatx4 acc[8];
#pragma unroll
    for (int nt = 0; nt < 8; nt++) acc[nt] = (floatx4){0.f, 0.f, 0.f, 0.f};

    for (int ks = 0; ks < 16; ks++) {
        float4 p = *(const float4*)(fp + ks * 32);
        float4 q = *(const float4*)(fp + ks * 32 + 4);
        short8 a;
        a[0] = (short)f2bf(p.x); a[1] = (short)f2bf(p.y);
        a[2] = (short)f2bf(p.z); a[3] = (short)f2bf(p.w);
        a[4] = (short)f2bf(q.x); a[5] = (short)f2bf(q.y);
        a[6] = (short)f2bf(q.z); a[7] = (short)f2bf(q.w);
#pragma unroll
        for (int nt = 0; nt < 8; nt++) {
            short8 b = *(const short8*)(Wt0 + (size_t)(nt * 16 + l16) * IN_DIM + ks * 32 + quad * 8);
            acc[nt] = __builtin_amdgcn_mfma_f32_16x16x32_bf16(a, b, acc[nt], 0, 0, 0);
        }
    }
#pragma unroll
    for (int nt = 0; nt < 8; nt++) {
        int col = nt * 16 + l16;
        float bias = b0[col];
#pragma unroll
        for (int r = 0; r < 4; r++) {
            int row = row0 + quad * 4 + r;
            float v = acc[nt][r] + bias;
            v = v > 0.f ? v : 0.f;
            ushort_t u = f2bf(v);
            if (row < M_PAD) {
                h0b[(size_t)row * HDIM + col] = u;
                xab[(size_t)row * HDIM + col] = u;
            }
        }
    }
}

// ---------------- SpMM + mix: sup = 0.9*(A x) + 0.1*h0 (bf16 in/out) ----------------

__global__ void spmm_kernel(const int* __restrict__ row_start,
                            const int* __restrict__ perm_src,
                            const float* __restrict__ perm_w,
                            const unsigned* __restrict__ xb,   // [M][64] bf16x2
                            const unsigned* __restrict__ h0b,
                            unsigned* __restrict__ supb) {
    int row  = blockIdx.x * 4 + (threadIdx.x >> 6);
    int lane = threadIdx.x & 63;
    if (row >= N_NODES) return;
    int e0 = row_start[row], e1 = row_start[row + 1];
    float a0 = 0.f, a1 = 0.f;
    for (int base = e0; base < e1; base += 64) {
        int navail = e1 - base;
        int s = 0; float w = 0.f;
        if (lane < navail) { s = perm_src[base + lane]; w = perm_w[base + lane]; }
        int cnt = navail < 64 ? navail : 64;
        for (int j = 0; j < cnt; j++) {
            int   sj = __shfl(s, j);
            float wj = __shfl(w, j);
            unsigned v = xb[(size_t)sj * 64 + lane];
            a0 += wj * __uint_as_float(v << 16);
            a1 += wj * __uint_as_float(v & 0xFFFF0000u);
        }
    }
    unsigned h = h0b[(size_t)row * 64 + lane];
    float o0 = 0.9f * a0 + 0.1f * __uint_as_float(h << 16);
    float o1 = 0.9f * a1 + 0.1f * __uint_as_float(h & 0xFFFF0000u);
    supb[(size_t)row * 64 + lane] = pack2(o0, o1);
}

// ---------- layer GEMM: x = relu(beta*(S@W) + (1-beta)*S), bf16 in/out ----------

__global__ void layer_gemm_mfma(const ushort_t* __restrict__ S, const ushort_t* __restrict__ Wt,
                                ushort_t* __restrict__ X, float beta) {
    int wave = threadIdx.x >> 6;
    int lane = threadIdx.x & 63;
    int quad = lane >> 4, l16 = lane & 15;
    int row0 = blockIdx.x * 64 + wave * 16;

    int arow = row0 + l16; if (arow > N_NODES - 1) arow = N_NODES - 1;
    const ushort_t* ap = S + (size_t)arow * HDIM + quad * 8;
    short8 afrag[4];
#pragma unroll
    for (int ks = 0; ks < 4; ks++) afrag[ks] = *(const short8*)(ap + ks * 32);

    floatx4 acc[8];
#pragma unroll
    for (int nt = 0; nt < 8; nt++) {
        const ushort_t* bp = Wt + (size_t)(nt * 16 + l16) * HDIM + quad * 8;
        floatx4 c = (floatx4){0.f, 0.f, 0.f, 0.f};
#pragma unroll
        for (int ks = 0; ks < 4; ks++) {
            short8 b = *(const short8*)(bp + ks * 32);
            c = __builtin_amdgcn_mfma_f32_16x16x32_bf16(afrag[ks], b, c, 0, 0, 0);
        }
        acc[nt] = c;
    }
    float g = 1.f - beta;
#pragma unroll
    for (int nt = 0; nt < 8; nt++) {
        int col = nt * 16 + l16;
#pragma unroll
        for (int r = 0; r < 4; r++) {
            int row = row0 + quad * 4 + r;
            if (row < N_NODES) {
                float s = bf2f(S[(size_t)row * HDIM + col]);
                float v = beta * acc[nt][r] + g * s;
                v = v > 0.f ? v : 0.f;
                X[(size_t)row * HDIM + col] = f2bf(v);
            }
        }
    }
}

// ---------------- fc1: out = x @ W1 + b1 (fp32 out), N padded 40->48 ----------------

__global__ void fc1_mfma(const ushort_t* __restrict__ X, const ushort_t* __restrict__ Wt1,
                         const float* __restrict__ b1, float* __restrict__ out) {
    int wave = threadIdx.x >> 6;
    int lane = threadIdx.x & 63;
    int quad = lane >> 4, l16 = lane & 15;
    int row0 = blockIdx.x * 64 + wave * 16;

    int arow = row0 + l16; if (arow > N_NODES - 1) arow = N_NODES - 1;
    const ushort_t* ap = X + (size_t)arow * HDIM + quad * 8;
    short8 afrag[4];
#pragma unroll
    for (int ks = 0; ks < 4; ks++) afrag[ks] = *(const short8*)(ap + ks * 32);

    floatx4 acc[3];
#pragma unroll
    for (int nt = 0; nt < 3; nt++) {
        const ushort_t* bp = Wt1 + (size_t)(nt * 16 + l16) * HDIM + quad * 8;
        floatx4 c = (floatx4){0.f, 0.f, 0.f, 0.f};
#pragma unroll
        for (int ks = 0; ks < 4; ks++) {
            short8 b = *(const short8*)(bp + ks * 32);
            c = __builtin_amdgcn_mfma_f32_16x16x32_bf16(afrag[ks], b, c, 0, 0, 0);
        }
        acc[nt] = c;
    }
#pragma unroll
    for (int nt = 0; nt < 3; nt++) {
        int col = nt * 16 + l16;
        if (col < CDIM) {
            float bias = b1[col];
#pragma unroll
            for (int r = 0; r < 4; r++) {
                int row = row0 + quad * 4 + r;
                if (row < N_NODES)
                    out[(size_t)row * CDIM + col] = acc[nt][r] + bias;
            }
        }
    }
}

// ---------------- launch ----------------

extern "C" void kernel_launch(void* const* d_in, const int* in_sizes, int n_in,
                              void* d_out, int out_size, void* d_ws, size_t ws_size,
                              hipStream_t stream) {
    const float* F     = (const float*)d_in[0];
    const int*   ei    = (const int*)d_in[1];
    const float* normA = (const float*)d_in[2];
    const float* W0    = (const float*)d_in[3];
    const float* b0    = (const float*)d_in[4];
    const float* convW = (const float*)d_in[5];
    const float* W1    = (const float*)d_in[6];
    const float* b1    = (const float*)d_in[7];
    float*       out   = (float*)d_out;

    // workspace layout (bf16 trunk), all 16B-aligned
    ushort_t* h0b  = (ushort_t*)d_ws;                     // M_PAD*128
    ushort_t* xab  = h0b + (size_t)M_PAD * HDIM;
    ushort_t* xbb  = xab + (size_t)M_PAD * HDIM;
    ushort_t* Wt0  = xbb + (size_t)M_PAD * HDIM;          // 128*512
    ushort_t* WtL  = Wt0 + 128 * 512;                     // 8*128*128
    ushort_t* Wt1  = WtL + 8 * 128 * 128;                 // 48*128
    int*   row_start = (int*)(Wt1 + 48 * 128);
    int*   cursor    = row_start + (N_NODES + 8);
    int*   perm_src  = cursor + (N_NODES + 8);
    float* perm_w    = (float*)(perm_src + E_EDGES);

    // CSR build
    hipMemsetAsync(cursor, 0, N_NODES * sizeof(int), stream);
    hist_kernel<<<(E_EDGES + 255) / 256, 256, 0, stream>>>(ei + E_EDGES, cursor);
    scan_kernel<<<1, 1024, 0, stream>>>(cursor, row_start);
    hipMemcpyAsync(cursor, row_start, N_NODES * sizeof(int),
                   hipMemcpyDeviceToDevice, stream);
    scatter_kernel<<<(E_EDGES + 255) / 256, 256, 0, stream>>>(ei, normA, cursor,
                                                              perm_src, perm_w);
    prep_weights<<<(128 * 512 + 8 * 128 * 128 + 48 * 128 + 255) / 256, 256, 0, stream>>>(
        W0, convW, W1, Wt0, WtL, Wt1);

    fc0_mfma<<<M_PAD / 64, 256, 0, stream>>>(F, Wt0, b0, h0b, xab);

    for (int i = 0; i < LAYERS; i++) {
        float beta = logf(0.5f / (float)(i + 1) + 1.0f);
        spmm_kernel<<<(N_NODES + 3) / 4, 256, 0, stream>>>(
            row_start, perm_src, perm_w, (const unsigned*)xab, (const unsigned*)h0b,
            (unsigned*)xbb);
        layer_gemm_mfma<<<M_PAD / 64, 256, 0, stream>>>(
            xbb, WtL + (size_t)i * HDIM * HDIM, xab, beta);
    }

    fc1_mfma<<<M_PAD / 64, 256, 0, stream>>>(xab, Wt1, b1, out);
}

// Round 4
// 832.773 us; speedup vs baseline: 1.8655x; 1.2591x over previous
//
#include <hip/hip_runtime.h>
#include <hip/hip_bf16.h>
#include <math.h>

#define N_NODES 50000
#define M_PAD   50048           // 782 blocks * 64 rows
#define E_EDGES 800000
#define IN_DIM  512
#define HDIM    128
#define CDIM    40
#define LAYERS  8

typedef __attribute__((ext_vector_type(8))) short short8;
typedef __attribute__((ext_vector_type(4))) short short4v;
typedef __attribute__((ext_vector_type(4))) float floatx4;
typedef unsigned short ushort_t;

__device__ inline float bf2f(unsigned short u) {
    return __uint_as_float(((unsigned)u) << 16);
}
__device__ inline unsigned short f2bf(float v) {
    __hip_bfloat16 b = __float2bfloat16(v);
    return *reinterpret_cast<unsigned short*>(&b);
}

// ---------------- CSR build ----------------

__global__ void hist_kernel(const int* __restrict__ dst, int* __restrict__ cnt) {
    int i = blockIdx.x * blockDim.x + threadIdx.x;
    if (i < E_EDGES) atomicAdd(&cnt[dst[i]], 1);
}

__global__ void scan_kernel(const int* __restrict__ cnt, int* __restrict__ row_start) {
    __shared__ int partial[1024];
    const int n = N_NODES;
    int t = threadIdx.x;
    int chunk = (n + 1023) >> 10;
    int lo = t * chunk;
    int hi = lo + chunk; if (hi > n) hi = n;
    int s = 0;
    for (int i = lo; i < hi; i++) s += cnt[i];
    partial[t] = s;
    __syncthreads();
    for (int d = 1; d < 1024; d <<= 1) {
        int v = (t >= d) ? partial[t - d] : 0;
        __syncthreads();
        partial[t] += v;
        __syncthreads();
    }
    int base = (t > 0) ? partial[t - 1] : 0;
    for (int i = lo; i < hi; i++) { row_start[i] = base; base += cnt[i]; }
    if (t == 1023) row_start[n] = partial[1023];
}

__global__ void scatter_kernel(const int* __restrict__ ei, const float* __restrict__ normA,
                               int* __restrict__ cursor, int2* __restrict__ perm) {
    int i = blockIdx.x * blockDim.x + threadIdx.x;
    if (i >= E_EDGES) return;
    int d = ei[E_EDGES + i];
    int idx = atomicAdd(&cursor[d], 1);
    perm[idx] = make_int2(ei[i], __float_as_int(normA[i]));
}

// ---------------- weight prep: transpose + bf16 convert ----------------

__global__ void prep_weights(const float* __restrict__ W0, const float* __restrict__ convW,
                             const float* __restrict__ W1,
                             ushort_t* __restrict__ Wt0, ushort_t* __restrict__ WtL,
                             ushort_t* __restrict__ Wt1) {
    int i = blockIdx.x * blockDim.x + threadIdx.x;
    if (i < 128 * 512) {
        int n = i >> 9, k = i & 511;
        Wt0[i] = f2bf(W0[k * HDIM + n]);
        return;
    }
    int j = i - 128 * 512;
    if (j < 8 * 128 * 128) {
        int l = j >> 14, rem = j & 16383, n = rem >> 7, k = rem & 127;
        WtL[j] = f2bf(convW[l * 16384 + k * HDIM + n]);
        return;
    }
    int m = j - 8 * 128 * 128;
    if (m < 48 * 128) {
        int n = m >> 7, k = m & 127;
        Wt1[m] = (n < CDIM) ? f2bf(W1[k * CDIM + n]) : (ushort_t)0;
    }
}

// ---------------- fc0: x = relu(F @ W0 + b0) -> h0b, xab (bf16) ----------------
// block = 256 thr (4 waves), 64 rows x 128 cols; K=512 staged in 4 LDS chunks of 128

#define SROW 136   // 128 + 8 pad (keeps ds_read_b128 groups spread)

__global__ void fc0_mfma(const float* __restrict__ F, const ushort_t* __restrict__ Wt0,
                         const float* __restrict__ b0,
                         ushort_t* __restrict__ h0b, ushort_t* __restrict__ xab) {
    __shared__ short sA[64][SROW];   // 17.4 KB
    int t = threadIdx.x;
    int wave = t >> 6, lane = t & 63;
    int quad = lane >> 4, l16 = lane & 15;
    int row0 = blockIdx.x * 64;

    floatx4 acc[8];
#pragma unroll
    for (int nt = 0; nt < 8; nt++) acc[nt] = (floatx4){0.f, 0.f, 0.f, 0.f};

    int rbase = t >> 5;        // 0..7
    int c4    = (t & 31) * 4;  // 0..124

    for (int kc = 0; kc < 4; kc++) {
        // stage 64 rows x 128 f32 -> bf16 LDS (coalesced float4 loads)
#pragma unroll
        for (int rr = 0; rr < 8; rr++) {
            int r = rbase + rr * 8;
            int fr = row0 + r; if (fr > N_NODES - 1) fr = N_NODES - 1;
            float4 v = *(const float4*)(F + (size_t)fr * IN_DIM + kc * 128 + c4);
            short4v s;
            s[0] = (short)f2bf(v.x); s[1] = (short)f2bf(v.y);
            s[2] = (short)f2bf(v.z); s[3] = (short)f2bf(v.w);
            *(short4v*)&sA[r][c4] = s;
        }
        __syncthreads();
#pragma unroll
        for (int ks = 0; ks < 4; ks++) {
            short8 a = *(const short8*)&sA[wave * 16 + l16][ks * 32 + quad * 8];
#pragma unroll
            for (int nt = 0; nt < 8; nt++) {
                short8 b = *(const short8*)(Wt0 + (size_t)(nt * 16 + l16) * IN_DIM +
                                            kc * 128 + ks * 32 + quad * 8);
                acc[nt] = __builtin_amdgcn_mfma_f32_16x16x32_bf16(a, b, acc[nt], 0, 0, 0);
            }
        }
        __syncthreads();
    }
#pragma unroll
    for (int nt = 0; nt < 8; nt++) {
        int col = nt * 16 + l16;
        float bias = b0[col];
#pragma unroll
        for (int r = 0; r < 4; r++) {
            int row = row0 + wave * 16 + quad * 4 + r;
            float v = acc[nt][r] + bias;
            v = v > 0.f ? v : 0.f;
            ushort_t u = f2bf(v);
            h0b[(size_t)row * HDIM + col] = u;
            xab[(size_t)row * HDIM + col] = u;
        }
    }
}

// ---------------- SpMM + mix: sup = 0.9*(A x) + 0.1*h0 (bf16 in/out) ----------------
// wave = 1 dst row; 4 edge slots x 16 lanes; lane gathers 16B (8 cols)

__global__ void spmm_kernel(const int* __restrict__ row_start,
                            const int2* __restrict__ perm,
                            const ushort_t* __restrict__ xb,
                            const ushort_t* __restrict__ h0b,
                            ushort_t* __restrict__ supb) {
    int row  = blockIdx.x * 4 + (threadIdx.x >> 6);
    int lane = threadIdx.x & 63;
    int slot = lane >> 4, sl = lane & 15;
    if (row >= N_NODES) return;
    int e0 = row_start[row], e1 = row_start[row + 1];

    float acc[8];
#pragma unroll
    for (int c = 0; c < 8; c++) acc[c] = 0.f;

    int e = e0 + slot;
    int2 pw = make_int2(0, 0);
    if (e < e1) pw = perm[e];
    while (e < e1) {
        int en = e + 4;
        int2 pwn = make_int2(0, 0);
        if (en < e1) pwn = perm[en];               // prefetch next edge meta
        float w = __int_as_float(pw.y);
        short8 v = *(const short8*)(xb + (size_t)pw.x * HDIM + sl * 8);
#pragma unroll
        for (int c = 0; c < 8; c++) acc[c] += w * bf2f((ushort_t)v[c]);
        pw = pwn; e = en;
    }
    // reduce across the 4 slots (lanes sl, sl+16, sl+32, sl+48)
#pragma unroll
    for (int c = 0; c < 8; c++) {
        acc[c] += __shfl_xor(acc[c], 16);
        acc[c] += __shfl_xor(acc[c], 32);
    }
    if (slot == 0) {
        short8 h = *(const short8*)(h0b + (size_t)row * HDIM + sl * 8);
        short8 o;
#pragma unroll
        for (int c = 0; c < 8; c++)
            o[c] = (short)f2bf(0.9f * acc[c] + 0.1f * bf2f((ushort_t)h[c]));
        *(short8*)(supb + (size_t)row * HDIM + sl * 8) = o;
    }
}

// ---------- layer GEMM: x = relu(beta*(S@W) + (1-beta)*S), bf16 in/out ----------

__global__ void layer_gemm_mfma(const ushort_t* __restrict__ S, const ushort_t* __restrict__ Wt,
                                ushort_t* __restrict__ X, float beta) {
    __shared__ short sS[64][SROW];   // 17.4 KB
    int t = threadIdx.x;
    int wave = t >> 6, lane = t & 63;
    int quad = lane >> 4, l16 = lane & 15;
    int row0 = blockIdx.x * 64;

    // stage 64 rows x 128 bf16, coalesced 16B loads (4 per thread)
#pragma unroll
    for (int i = 0; i < 4; i++) {
        int idx = t + i * 256;           // 0..1023
        int r = idx >> 4, c8 = (idx & 15) * 8;
        *(short8*)&sS[r][c8] = *(const short8*)(S + (size_t)(row0 + r) * HDIM + c8);
    }
    __syncthreads();

    short8 afrag[4];
#pragma unroll
    for (int ks = 0; ks < 4; ks++)
        afrag[ks] = *(const short8*)&sS[wave * 16 + l16][ks * 32 + quad * 8];

    floatx4 acc[8];
#pragma unroll
    for (int nt = 0; nt < 8; nt++) {
        const ushort_t* bp = Wt + (size_t)(nt * 16 + l16) * HDIM + quad * 8;
        floatx4 c = (floatx4){0.f, 0.f, 0.f, 0.f};
#pragma unroll
        for (int ks = 0; ks < 4; ks++) {
            short8 b = *(const short8*)(bp + ks * 32);
            c = __builtin_amdgcn_mfma_f32_16x16x32_bf16(afrag[ks], b, c, 0, 0, 0);
        }
        acc[nt] = c;
    }
    float g = 1.f - beta;
#pragma unroll
    for (int nt = 0; nt < 8; nt++) {
        int col = nt * 16 + l16;
#pragma unroll
        for (int r = 0; r < 4; r++) {
            int lrow = wave * 16 + quad * 4 + r;
            float s = bf2f((ushort_t)sS[lrow][col]);
            float v = beta * acc[nt][r] + g * s;
            v = v > 0.f ? v : 0.f;
            X[(size_t)(row0 + lrow) * HDIM + col] = f2bf(v);
        }
    }
}

// ---------------- fc1: out = x @ W1 + b1 (fp32 out), N padded 40->48 ----------------

__global__ void fc1_mfma(const ushort_t* __restrict__ X, const ushort_t* __restrict__ Wt1,
                         const float* __restrict__ b1, float* __restrict__ out) {
    int wave = threadIdx.x >> 6;
    int lane = threadIdx.x & 63;
    int quad = lane >> 4, l16 = lane & 15;
    int row0 = blockIdx.x * 64 + wave * 16;

    int arow = row0 + l16; if (arow > N_NODES - 1) arow = N_NODES - 1;
    const ushort_t* ap = X + (size_t)arow * HDIM + quad * 8;
    short8 afrag[4];
#pragma unroll
    for (int ks = 0; ks < 4; ks++) afrag[ks] = *(const short8*)(ap + ks * 32);

    floatx4 acc[3];
#pragma unroll
    for (int nt = 0; nt < 3; nt++) {
        const ushort_t* bp = Wt1 + (size_t)(nt * 16 + l16) * HDIM + quad * 8;
        floatx4 c = (floatx4){0.f, 0.f, 0.f, 0.f};
#pragma unroll
        for (int ks = 0; ks < 4; ks++) {
            short8 b = *(const short8*)(bp + ks * 32);
            c = __builtin_amdgcn_mfma_f32_16x16x32_bf16(afrag[ks], b, c, 0, 0, 0);
        }
        acc[nt] = c;
    }
#pragma unroll
    for (int nt = 0; nt < 3; nt++) {
        int col = nt * 16 + l16;
        if (col < CDIM) {
            float bias = b1[col];
#pragma unroll
            for (int r = 0; r < 4; r++) {
                int row = row0 + quad * 4 + r;
                if (row < N_NODES)
                    out[(size_t)row * CDIM + col] = acc[nt][r] + bias;
            }
        }
    }
}

// ---------------- launch ----------------

extern "C" void kernel_launch(void* const* d_in, const int* in_sizes, int n_in,
                              void* d_out, int out_size, void* d_ws, size_t ws_size,
                              hipStream_t stream) {
    const float* F     = (const float*)d_in[0];
    const int*   ei    = (const int*)d_in[1];
    const float* normA = (const float*)d_in[2];
    const float* W0    = (const float*)d_in[3];
    const float* b0    = (const float*)d_in[4];
    const float* convW = (const float*)d_in[5];
    const float* W1    = (const float*)d_in[6];
    const float* b1    = (const float*)d_in[7];
    float*       out   = (float*)d_out;

    // workspace layout (bf16 trunk), 16B-aligned
    ushort_t* h0b  = (ushort_t*)d_ws;                     // M_PAD*128
    ushort_t* xab  = h0b + (size_t)M_PAD * HDIM;
    ushort_t* xbb  = xab + (size_t)M_PAD * HDIM;
    ushort_t* Wt0  = xbb + (size_t)M_PAD * HDIM;          // 128*512
    ushort_t* WtL  = Wt0 + 128 * 512;                     // 8*128*128
    ushort_t* Wt1  = WtL + 8 * 128 * 128;                 // 48*128
    int*   row_start = (int*)(Wt1 + 48 * 128);
    int*   cursor    = row_start + (N_NODES + 8);
    int2*  perm      = (int2*)(cursor + (N_NODES + 8));   // 8B-aligned

    // CSR build
    hipMemsetAsync(cursor, 0, N_NODES * sizeof(int), stream);
    hist_kernel<<<(E_EDGES + 255) / 256, 256, 0, stream>>>(ei + E_EDGES, cursor);
    scan_kernel<<<1, 1024, 0, stream>>>(cursor, row_start);
    hipMemcpyAsync(cursor, row_start, N_NODES * sizeof(int),
                   hipMemcpyDeviceToDevice, stream);
    scatter_kernel<<<(E_EDGES + 255) / 256, 256, 0, stream>>>(ei, normA, cursor, perm);
    prep_weights<<<(128 * 512 + 8 * 128 * 128 + 48 * 128 + 255) / 256, 256, 0, stream>>>(
        W0, convW, W1, Wt0, WtL, Wt1);

    fc0_mfma<<<M_PAD / 64, 256, 0, stream>>>(F, Wt0, b0, h0b, xab);

    for (int i = 0; i < LAYERS; i++) {
        float beta = logf(0.5f / (float)(i + 1) + 1.0f);
        spmm_kernel<<<(N_NODES + 3) / 4, 256, 0, stream>>>(
            row_start, perm, xab, h0b, xbb);
        layer_gemm_mfma<<<M_PAD / 64, 256, 0, stream>>>(
            xbb, WtL + (size_t)i * HDIM * HDIM, xab, beta);
    }

    fc1_mfma<<<M_PAD / 64, 256, 0, stream>>>(xab, Wt1, b1, out);
}